// Round 1
// baseline (245.066 us; speedup 1.0000x reference)
//
#include <hip/hip_runtime.h>
#include <hip/hip_bf16.h>

// ELBO: out = -sum(log(decoded[b, context[b,c]])) + sum_kl
// kl[b,d] = log(sigma_x/sigma_l) + (sigma_l^2 + (mu_l - mu_x)^2) / (2 sigma_x^2) - 0.5
// B=1024, C=10, V=50257, D=128. Output: single fp32 scalar.

#define B_ 1024
#define C_ 10
#define V_ 50257
#define D_ 128

__global__ __launch_bounds__(256) void elbo_kernel(
    const int* __restrict__ context,
    const float* __restrict__ mu_l,
    const float* __restrict__ sig_l,
    const float* __restrict__ mu_x,
    const float* __restrict__ sig_x,
    const float* __restrict__ decoded,
    float* __restrict__ out)
{
    const int tid = blockIdx.x * blockDim.x + threadIdx.x;
    const int nth = gridDim.x * blockDim.x;

    float local = 0.0f;

    // KL terms over B*D = 131072 elements (coalesced, 2 iters/thread at 65536 threads)
    for (int i = tid; i < B_ * D_; i += nth) {
        float ml = mu_l[i];
        float sl = sig_l[i];
        float mx = mu_x[i];   // (B,1,D) flat == (B,D) flat
        float sx = sig_x[i];
        float diff = ml - mx;
        local += __logf(sx / sl) + (sl * sl + diff * diff) / (2.0f * sx * sx) - 0.5f;
    }

    // Gather-log terms over B*C = 10240 elements
    for (int i = tid; i < B_ * C_; i += nth) {
        int b = i / C_;
        int idx = context[i];
        local -= __logf(decoded[(size_t)b * V_ + idx]);
    }

    // wave-64 butterfly-ish down-reduce
    for (int off = 32; off > 0; off >>= 1)
        local += __shfl_down(local, off, 64);

    __shared__ float wsum[4];
    int lane = threadIdx.x & 63;
    int wid  = threadIdx.x >> 6;
    if (lane == 0) wsum[wid] = local;
    __syncthreads();

    if (threadIdx.x == 0)
        atomicAdd(out, wsum[0] + wsum[1] + wsum[2] + wsum[3]);
}

extern "C" void kernel_launch(void* const* d_in, const int* in_sizes, int n_in,
                              void* d_out, int out_size, void* d_ws, size_t ws_size,
                              hipStream_t stream) {
    const int*   context = (const int*)  d_in[0];
    const float* mu_l    = (const float*)d_in[1];
    const float* sig_l   = (const float*)d_in[2];
    const float* mu_x    = (const float*)d_in[3];
    const float* sig_x   = (const float*)d_in[4];
    const float* decoded = (const float*)d_in[5];
    float* out = (float*)d_out;

    // d_out is poisoned 0xAA before every timed call — zero it on-stream.
    hipMemsetAsync(out, 0, sizeof(float), stream);

    elbo_kernel<<<256, 256, 0, stream>>>(context, mu_l, sig_l, mu_x, sig_x,
                                         decoded, out);
}

// Round 2
// 242.872 us; speedup vs baseline: 1.0090x; 1.0090x over previous
//
#include <hip/hip_runtime.h>
#include <hip/hip_bf16.h>

// ELBO: out = -sum(log(decoded[b, context[b,c]])) + sum_kl
// kl[b,d] = log(sigma_x/sigma_l) + (sigma_l^2 + (mu_l - mu_x)^2) / (2 sigma_x^2) - 0.5
// B=1024, C=10, V=50257, D=128. Output: single fp32 scalar.
//
// Design: 2 dispatches, no memset, no same-address atomics.
//   k1: 128 blocks x 256 threads. Each thread handles exactly one float4 of
//       the B*D=131072 KL elements (32768 float4s) + at most one gather term.
//       Block-reduce -> partial[blockIdx] in d_ws.
//   k2: 1 block reduces the 128 partials, plain store to d_out (overwrites
//       the 0xAA poison every call).

#define B_ 1024
#define C_ 10
#define V_ 50257
#define D_ 128
#define NB1 128   // blocks in kernel 1; 128*256*4 == B_*D_

__global__ __launch_bounds__(256) void elbo_partial(
    const int* __restrict__ context,
    const float4* __restrict__ mu_l,
    const float4* __restrict__ sig_l,
    const float4* __restrict__ mu_x,
    const float4* __restrict__ sig_x,
    const float* __restrict__ decoded,
    float* __restrict__ partial)
{
    const int tid = blockIdx.x * 256 + threadIdx.x;   // 0..32767

    // --- KL terms: one float4 from each array, fully coalesced 16B/lane ---
    float4 ml = mu_l[tid];
    float4 sl = sig_l[tid];
    float4 mx = mu_x[tid];    // (B,1,D) flat == (B,D) flat
    float4 sx = sig_x[tid];

    float local;
    {
        float d0 = ml.x - mx.x, d1 = ml.y - mx.y, d2 = ml.z - mx.z, d3 = ml.w - mx.w;
        float t0 = __logf(sx.x / sl.x) + (sl.x * sl.x + d0 * d0) / (2.0f * sx.x * sx.x) - 0.5f;
        float t1 = __logf(sx.y / sl.y) + (sl.y * sl.y + d1 * d1) / (2.0f * sx.y * sx.y) - 0.5f;
        float t2 = __logf(sx.z / sl.z) + (sl.z * sl.z + d2 * d2) / (2.0f * sx.z * sx.z) - 0.5f;
        float t3 = __logf(sx.w / sl.w) + (sl.w * sl.w + d3 * d3) / (2.0f * sx.w * sx.w) - 0.5f;
        local = (t0 + t1) + (t2 + t3);
    }

    // --- gather-log terms: B*C = 10240 < 32768 threads, one each ---
    if (tid < B_ * C_) {
        int b = tid / C_;                 // compiler lowers to magic-mul
        int idx = context[tid];
        local -= __logf(decoded[(size_t)b * V_ + idx]);
    }

    // --- wave-64 reduce, then 4 waves -> 1 via LDS ---
    for (int off = 32; off > 0; off >>= 1)
        local += __shfl_down(local, off, 64);

    __shared__ float wsum[4];
    int lane = threadIdx.x & 63;
    int wid  = threadIdx.x >> 6;
    if (lane == 0) wsum[wid] = local;
    __syncthreads();

    if (threadIdx.x == 0)
        partial[blockIdx.x] = (wsum[0] + wsum[1]) + (wsum[2] + wsum[3]);
}

__global__ __launch_bounds__(128) void elbo_final(
    const float* __restrict__ partial,
    float* __restrict__ out)
{
    float local = partial[threadIdx.x];   // 128 partials, 2 waves
    for (int off = 32; off > 0; off >>= 1)
        local += __shfl_down(local, off, 64);

    __shared__ float wsum[2];
    if ((threadIdx.x & 63) == 0) wsum[threadIdx.x >> 6] = local;
    __syncthreads();

    if (threadIdx.x == 0)
        out[0] = wsum[0] + wsum[1];       // plain store overwrites poison
}

extern "C" void kernel_launch(void* const* d_in, const int* in_sizes, int n_in,
                              void* d_out, int out_size, void* d_ws, size_t ws_size,
                              hipStream_t stream) {
    const int*    context = (const int*)   d_in[0];
    const float4* mu_l    = (const float4*)d_in[1];
    const float4* sig_l   = (const float4*)d_in[2];
    const float4* mu_x    = (const float4*)d_in[3];
    const float4* sig_x   = (const float4*)d_in[4];
    const float*  decoded = (const float*) d_in[5];
    float* partial = (float*)d_ws;
    float* out     = (float*)d_out;

    elbo_partial<<<NB1, 256, 0, stream>>>(context, mu_l, sig_l, mu_x, sig_x,
                                          decoded, partial);
    elbo_final<<<1, 128, 0, stream>>>(partial, out);
}